// Round 18
// baseline (206.675 us; speedup 1.0000x reference)
//
#include <hip/hip_runtime.h>
#include <hip/hip_bf16.h>

typedef __bf16 bf16x8 __attribute__((ext_vector_type(8)));
typedef float f32x4 __attribute__((ext_vector_type(4)));

#define M_TOK 16384   // 8 * 2048 tokens
#define CHUNK 32
#define NCHUNK 64     // 2048 / 32

__device__ __forceinline__ void gload16(const void* g, void* l) {
    __builtin_amdgcn_global_load_lds(
        (const __attribute__((address_space(1))) void*)g,
        (__attribute__((address_space(3))) void*)l, 16, 0, 0);
}

__device__ __forceinline__ float sigmoidf_(float v) { return 1.f / (1.f + __expf(-v)); }

// ======== fused: matpow32 (blocks 0..127, dispatched FIRST) + all converts (128..9759) ========
__global__ __launch_bounds__(256)
void conv_pow(const float* __restrict__ A, float* __restrict__ A32,
              const float* s0, const float* s1, const float* s2, const float* s3,
              const float* s4, const float* s5, const float* s6,
              __hip_bfloat16* d0, __hip_bfloat16* d1, __hip_bfloat16* d2,
              __hip_bfloat16* d3, __hip_bfloat16* d4, __hip_bfloat16* d5,
              __hip_bfloat16* d6) {
    __shared__ __align__(16) float v[2][128];
    const int tid = threadIdx.x;
    if (blockIdx.x < 128) {
        const int col = blockIdx.x;
        f32x4 pr[32];
        if (tid < 128) {
            #pragma unroll
            for (int k = 0; k < 32; ++k)
                pr[k] = *reinterpret_cast<const f32x4*>(&A[tid * 128 + k * 4]);
            v[0][tid] = A[tid * 128 + col];
        }
        __syncthreads();
        int cur = 0;
        for (int it = 0; it < 31; ++it) {
            if (tid < 128) {
                const f32x4* hv = reinterpret_cast<const f32x4*>(v[cur]);
                f32x4 s0_{}, s1_{}, s2_{}, s3_{};
                #pragma unroll
                for (int k = 0; k < 32; k += 4) {
                    s0_ += pr[k]     * hv[k];
                    s1_ += pr[k + 1] * hv[k + 1];
                    s2_ += pr[k + 2] * hv[k + 2];
                    s3_ += pr[k + 3] * hv[k + 3];
                }
                f32x4 ss = (s0_ + s1_) + (s2_ + s3_);
                v[cur ^ 1][tid] = ss[0] + ss[1] + ss[2] + ss[3];
            }
            __syncthreads();
            cur ^= 1;
        }
        if (tid < 128) A32[tid * 128 + col] = v[cur][tid];
        return;
    }
    const int bid = blockIdx.x - 128;
    const float* s; __hip_bfloat16* d; int base;
    if      (bid < 8192) { s = s0; d = d0; base = 0;    }
    else if (bid < 8448) { s = s1; d = d1; base = 8192; }
    else if (bid < 8480) { s = s2; d = d2; base = 8448; }
    else if (bid < 8544) { s = s3; d = d3; base = 8480; }
    else if (bid < 8608) { s = s4; d = d4; base = 8544; }
    else if (bid < 9120) { s = s5; d = d5; base = 8608; }
    else                 { s = s6; d = d6; base = 9120; }
    size_t i = (size_t)(bid - base) * 256 + tid;
    const f32x4* p4 = reinterpret_cast<const f32x4*>(s) + i * 2;
    f32x4 a = p4[0], b = p4[1];
    union { __hip_bfloat16 h[8]; uint4 u; } o;
    o.h[0] = __float2bfloat16(a[0]); o.h[1] = __float2bfloat16(a[1]);
    o.h[2] = __float2bfloat16(a[2]); o.h[3] = __float2bfloat16(a[3]);
    o.h[4] = __float2bfloat16(b[0]); o.h[5] = __float2bfloat16(b[1]);
    o.h[6] = __float2bfloat16(b[2]); o.h[7] = __float2bfloat16(b[3]);
    *reinterpret_cast<uint4*>(d + i * 8) = o.u;
}

// ================= 128x128 m97-style GEMM (single-buffer, multi-block overlap) =========
// MODE 0: z1 = silu(X@W^T + b)        -> bf16 (N=512, K=1024)
// MODE 1: out = (X@Dw^T + Db + HS@Cw^T + Cb) * sigmoid(X@Gw^T + Gb) -> f32 (N=1024)
// 930 TF (R7). launch_bounds STAYS (256,2): R16 proved (256,3/4) caps VGPR at 84 -> spills.
template<int MODE>
__global__ __launch_bounds__(256, 2)
void gemm128(const __hip_bfloat16* __restrict__ X, const __hip_bfloat16* __restrict__ W,
             const __hip_bfloat16* __restrict__ Gw, const __hip_bfloat16* __restrict__ HS,
             const __hip_bfloat16* __restrict__ CW,
             const float* __restrict__ bias, const float* __restrict__ bias2,
             const float* __restrict__ biasG,
             float* __restrict__ outF, __hip_bfloat16* __restrict__ outB) {
    constexpr int N = (MODE == 0) ? 512 : 1024;
    constexpr int nN = N / 128;
    __shared__ __align__(16) char Xs[16384];
    __shared__ __align__(16) char Ws[16384];
    __shared__ __align__(16) char Gs[(MODE == 1) ? 16384 : 16];

    const int nwg  = gridDim.x;
    const int orig = blockIdx.x;
    const int v    = (orig & 7) * (nwg >> 3) + (orig >> 3);   // XCD-bijective (nwg%8==0)
    const size_t m0 = (size_t)(v / nN) * 128;
    const int    n0 = (v % nN) * 128;
    const int tid = threadIdx.x, lane = tid & 63, wid = tid >> 6;
    const int wm = wid >> 1, wn = wid & 1;
    const int lr = lane & 15, lg = lane >> 4;

    auto frag = [&](const char* base, int R, int kk) -> bf16x8 {
        int cb = (kk * 64 + lg * 16) ^ ((R & 7) << 4);
        return *reinterpret_cast<const bf16x8*>(base + R * 128 + cb);
    };

    const char* gx[4]; const char* gw[4]; const char* gg[4];
    char* lx[4]; char* lw[4]; char* lg_[4];
    int rowq[4], cbq[4];
    #pragma unroll
    for (int j = 0; j < 4; ++j) {
        int q = tid + 256 * j;
        rowq[j] = q >> 3;
        cbq[j] = ((q & 7) * 16) ^ ((rowq[j] & 7) << 4);
        gx[j] = (const char*)(X + (m0 + rowq[j]) * (size_t)1024) + cbq[j];
        gw[j] = (const char*)(W + ((size_t)(n0 + rowq[j])) * 1024) + cbq[j];
        if constexpr (MODE == 1)
            gg[j] = (const char*)(Gw + ((size_t)(n0 + rowq[j])) * 1024) + cbq[j];
        lx[j] = Xs + q * 16; lw[j] = Ws + q * 16; lg_[j] = Gs + q * 16;
    }

    f32x4 accY[4][4] = {};
    f32x4 accG[(MODE == 1) ? 4 : 1][4] = {};

    for (int k0 = 0; k0 < 1024; k0 += 64) {
        __syncthreads();
        #pragma unroll
        for (int j = 0; j < 4; ++j) { gload16(gx[j], lx[j]); gx[j] += 128; }
        #pragma unroll
        for (int j = 0; j < 4; ++j) { gload16(gw[j], lw[j]); gw[j] += 128; }
        if constexpr (MODE == 1) {
            #pragma unroll
            for (int j = 0; j < 4; ++j) { gload16(gg[j], lg_[j]); gg[j] += 128; }
        }
        __syncthreads();
        #pragma unroll
        for (int kk = 0; kk < 2; ++kk) {
            bf16x8 af[4];
            #pragma unroll
            for (int m = 0; m < 4; ++m) af[m] = frag(Xs, wm*64 + m*16 + lr, kk);
            #pragma unroll
            for (int n = 0; n < 4; ++n) {
                bf16x8 bw = frag(Ws, wn*64 + n*16 + lr, kk);
                #pragma unroll
                for (int m = 0; m < 4; ++m)
                    accY[m][n] = __builtin_amdgcn_mfma_f32_16x16x32_bf16(af[m], bw, accY[m][n], 0, 0, 0);
                if constexpr (MODE == 1) {
                    bf16x8 bg = frag(Gs, wn*64 + n*16 + lr, kk);
                    #pragma unroll
                    for (int m = 0; m < 4; ++m)
                        accG[m][n] = __builtin_amdgcn_mfma_f32_16x16x32_bf16(af[m], bg, accG[m][n], 0, 0, 0);
                }
            }
        }
    }
    if constexpr (MODE == 1) {
        #pragma unroll
        for (int j = 0; j < 4; ++j) {
            gx[j] = (const char*)(HS + (m0 + rowq[j]) * (size_t)128) + cbq[j];
            gw[j] = (const char*)(CW + ((size_t)(n0 + rowq[j])) * 128) + cbq[j];
        }
        for (int k0 = 0; k0 < 128; k0 += 64) {
            __syncthreads();
            #pragma unroll
            for (int j = 0; j < 4; ++j) { gload16(gx[j], lx[j]); gx[j] += 128; }
            #pragma unroll
            for (int j = 0; j < 4; ++j) { gload16(gw[j], lw[j]); gw[j] += 128; }
            __syncthreads();
            #pragma unroll
            for (int kk = 0; kk < 2; ++kk) {
                bf16x8 af[4];
                #pragma unroll
                for (int m = 0; m < 4; ++m) af[m] = frag(Xs, wm*64 + m*16 + lr, kk);
                #pragma unroll
                for (int n = 0; n < 4; ++n) {
                    bf16x8 bw = frag(Ws, wn*64 + n*16 + lr, kk);
                    #pragma unroll
                    for (int m = 0; m < 4; ++m)
                        accY[m][n] = __builtin_amdgcn_mfma_f32_16x16x32_bf16(af[m], bw, accY[m][n], 0, 0, 0);
                }
            }
        }
    }

    #pragma unroll
    for (int m = 0; m < 4; ++m)
        #pragma unroll
        for (int n = 0; n < 4; ++n)
            #pragma unroll
            for (int rr = 0; rr < 4; ++rr) {
                size_t row = m0 + wm*64 + m*16 + lg*4 + rr;
                int col = n0 + wn*64 + n*16 + lr;
                if constexpr (MODE == 0) {
                    float vv = accY[m][n][rr] + bias[col];
                    outB[row * N + col] = __float2bfloat16(vv * sigmoidf_(vv));
                } else {
                    float y = accY[m][n][rr] + bias[col] + bias2[col];
                    float g = accG[m][n][rr] + biasG[col];
                    outF[row * 1024 + col] = y * sigmoidf_(g);
                }
            }
}

// ----- u = (x@B_w^T + B_b)*sigmoid(z1@s_w2^T + s_b2) [16384,128] + FUSED scan phase-1 -----
// 512 blocks; block v's 32-row tile IS scan chunk (b=v/64, c=v%64). After the u epilogue,
// u is parked in LDS (same bf16 rounding as global -> bitwise-identical scan) and threads
// 0-127 run the 32-step local scan (R8-proven form), emitting E[v] directly. Kills the
// ssm_phase1 launch + u round-trip.
__global__ __launch_bounds__(256, 2)
void gemm_u(const __hip_bfloat16* __restrict__ Z1, const __hip_bfloat16* __restrict__ W2,
            const float* __restrict__ b2,
            const __hip_bfloat16* __restrict__ X, const __hip_bfloat16* __restrict__ Bw,
            const float* __restrict__ Bb, const float* __restrict__ A,
            __hip_bfloat16* __restrict__ U, float* __restrict__ E) {
    __shared__ __align__(16) char As[32 * 128];    // 4 KB
    __shared__ __align__(16) char Bs[128 * 128];   // 16 KB (reused as uS in tail)
    __shared__ __align__(16) float hb[2][128];     // 1 KB
    const int orig = blockIdx.x;                 // nwg = 512
    const int v = (orig & 7) * 64 + (orig >> 3);
    const int m0 = v * 32;
    const int tid = threadIdx.x;
    const int wid = tid >> 6, lane = tid & 63;
    const int wm = wid >> 1, wn = wid & 1;
    const int lr = lane & 15, lg = lane >> 4;

    auto fragA = [&](int R, int kk) -> bf16x8 {
        int cb = (kk * 64 + lg * 16) ^ ((R & 7) << 4);
        return *reinterpret_cast<const bf16x8*>(As + R * 128 + cb);
    };
    auto fragB = [&](int R, int kk) -> bf16x8 {
        int cb = (kk * 64 + lg * 16) ^ ((R & 7) << 4);
        return *reinterpret_cast<const bf16x8*>(Bs + R * 128 + cb);
    };

    const int rowA = tid >> 3, cbA = ((tid & 7) * 16) ^ ((rowA & 7) << 4);
    char* lA = As + tid * 16;
    int rowB[4], cbB[4]; char* lB[4];
    #pragma unroll
    for (int j = 0; j < 4; ++j) {
        int q = tid + 256 * j;
        rowB[j] = q >> 3; cbB[j] = ((q & 7) * 16) ^ ((rowB[j] & 7) << 4);
        lB[j] = Bs + q * 16;
    }

    const char* ga; const char* gb[4];
    ga = (const char*)(Z1 + (size_t)(m0 + rowA) * 512) + cbA;
    #pragma unroll
    for (int j = 0; j < 4; ++j) gb[j] = (const char*)(W2 + (size_t)rowB[j] * 512) + cbB[j];

    f32x4 accS[4] = {};
    for (int k0 = 0; k0 < 512; k0 += 64) {
        __syncthreads();
        gload16(ga, lA); ga += 128;
        #pragma unroll
        for (int j = 0; j < 4; ++j) { gload16(gb[j], lB[j]); gb[j] += 128; }
        __syncthreads();
        #pragma unroll
        for (int kk = 0; kk < 2; ++kk) {
            bf16x8 af = fragA(wm*16 + lr, kk);
            #pragma unroll
            for (int n = 0; n < 4; ++n) {
                bf16x8 bf_ = fragB(wn*64 + n*16 + lr, kk);
                accS[n] = __builtin_amdgcn_mfma_f32_16x16x32_bf16(af, bf_, accS[n], 0, 0, 0);
            }
        }
    }
    #pragma unroll
    for (int n = 0; n < 4; ++n)
        #pragma unroll
        for (int r = 0; r < 4; ++r) {
            int col = wn*64 + n*16 + lr;
            accS[n][r] = sigmoidf_(accS[n][r] + b2[col]);
        }
    ga = (const char*)(X + (size_t)(m0 + rowA) * 1024) + cbA;
    #pragma unroll
    for (int j = 0; j < 4; ++j) gb[j] = (const char*)(Bw + (size_t)rowB[j] * 1024) + cbB[j];
    f32x4 accU[4] = {};
    for (int k0 = 0; k0 < 1024; k0 += 64) {
        __syncthreads();
        gload16(ga, lA); ga += 128;
        #pragma unroll
        for (int j = 0; j < 4; ++j) { gload16(gb[j], lB[j]); gb[j] += 128; }
        __syncthreads();
        #pragma unroll
        for (int kk = 0; kk < 2; ++kk) {
            bf16x8 af = fragA(wm*16 + lr, kk);
            #pragma unroll
            for (int n = 0; n < 4; ++n) {
                bf16x8 bf_ = fragB(wn*64 + n*16 + lr, kk);
                accU[n] = __builtin_amdgcn_mfma_f32_16x16x32_bf16(af, bf_, accU[n], 0, 0, 0);
            }
        }
    }
    __syncthreads();   // GEMM LDS reads done; Bs can be repurposed
    __hip_bfloat16* uS = reinterpret_cast<__hip_bfloat16*>(Bs);   // [32][128] bf16 (8 KB)
    #pragma unroll
    for (int n = 0; n < 4; ++n)
        #pragma unroll
        for (int r = 0; r < 4; ++r) {
            int row = wm*16 + lg*4 + r;      // local token 0..31
            int col = wn*64 + n*16 + lr;
            float uval = (accU[n][r] + Bb[col]) * accS[n][r];
            __hip_bfloat16 ub_ = __float2bfloat16(uval);
            U[(size_t)(m0 + row) * 128 + col] = ub_;
            uS[row * 128 + col] = ub_;
        }
    // ---- fused phase-1: 32-step local scan over this chunk (threads 0..127) ----
    f32x4 ar[32];
    if (tid < 128) {
        #pragma unroll
        for (int k = 0; k < 32; ++k)
            ar[k] = *reinterpret_cast<const f32x4*>(&A[tid * 128 + k * 4]);
        hb[0][tid] = 0.f;
    }
    __syncthreads();   // uS + hb[0] visible
    int cur = 0;
    for (int t = 0; t < CHUNK; ++t) {
        if (tid < 128) {
            const f32x4* hv = reinterpret_cast<const f32x4*>(hb[cur]);
            f32x4 s0{}, s1{}, s2{}, s3{};
            #pragma unroll
            for (int k = 0; k < 32; k += 4) {
                s0 += ar[k]     * hv[k];
                s1 += ar[k + 1] * hv[k + 1];
                s2 += ar[k + 2] * hv[k + 2];
                s3 += ar[k + 3] * hv[k + 3];
            }
            f32x4 ss = (s0 + s1) + (s2 + s3);
            float val = ss[0] + ss[1] + ss[2] + ss[3] + __bfloat162float(uS[t * 128 + tid]);
            hb[cur ^ 1][tid] = val;
        }
        __syncthreads();
        cur ^= 1;
    }
    if (tid < 128) E[(size_t)v * 128 + tid] = hb[cur][tid];
}

// ---------------- phase 2: per-batch combine over 64 chunks with A^32 ----------------
__global__ __launch_bounds__(128, 1) void ssm_phase2(const float* __restrict__ A32,
                                                     const float* __restrict__ E,
                                                     float* __restrict__ starts) {
    __shared__ __align__(16) float st[2][128];
    __shared__ __align__(16) float El[NCHUNK * 128];   // 32 KB
    const int tid = threadIdx.x, b = blockIdx.x;       // 8 blocks
    f32x4 ar[32];
    #pragma unroll
    for (int k = 0; k < 32; ++k) ar[k] = *reinterpret_cast<const f32x4*>(&A32[tid * 128 + k * 4]);
    const f32x4* Eg = reinterpret_cast<const f32x4*>(E + (size_t)b * NCHUNK * 128);
    #pragma unroll
    for (int q = 0; q < 16; ++q)
        reinterpret_cast<f32x4*>(El)[q * 128 + tid] = Eg[q * 128 + tid];
    st[0][tid] = 0.f;
    __syncthreads();
    int cur = 0;
    for (int c = 0; c < NCHUNK; ++c) {
        starts[((size_t)b * NCHUNK + c) * 128 + tid] = st[cur][tid];
        const f32x4* hv = reinterpret_cast<const f32x4*>(st[cur]);
        f32x4 s0{}, s1{}, s2{}, s3{};
        #pragma unroll
        for (int k = 0; k < 32; k += 4) {
            s0 += ar[k]     * hv[k];
            s1 += ar[k + 1] * hv[k + 1];
            s2 += ar[k + 2] * hv[k + 2];
            s3 += ar[k + 3] * hv[k + 3];
        }
        f32x4 ss = (s0 + s1) + (s2 + s3);
        float val = ss[0] + ss[1] + ss[2] + ss[3] + El[c * 128 + tid];
        st[cur ^ 1][tid] = val;
        __syncthreads();
        cur ^= 1;
    }
}

// ---------------- phase 3: re-run from starts, emit hs; CHUNK=32, 512 blocks ----------------
__global__ __launch_bounds__(128, 1) void ssm_phase3(const float* __restrict__ A,
                                                     const __hip_bfloat16* __restrict__ u,
                                                     const float* __restrict__ starts,
                                                     __hip_bfloat16* __restrict__ hs) {
    __shared__ __align__(16) float hb[2][128];
    __shared__ __align__(16) __hip_bfloat16 uL[CHUNK * 128];   // 8 KB
    const int tid = threadIdx.x;
    f32x4 ar[32];
    #pragma unroll
    for (int k = 0; k < 32; ++k) ar[k] = *reinterpret_cast<const f32x4*>(&A[tid * 128 + k * 4]);
    const int b = blockIdx.x >> 6, c = blockIdx.x & 63;
    const size_t tok0 = (size_t)b * 2048 + c * CHUNK;
    const __hip_bfloat16* up = u + tok0 * 128;
    #pragma unroll
    for (int q = 0; q < 4; ++q)
        gload16(up + ((size_t)(q * 128 + tid)) * 8, &uL[(q * 128 + tid) * 8]);
    hb[0][tid] = starts[(size_t)blockIdx.x * 128 + tid];
    __syncthreads();
    int cur = 0;
    for (int t = 0; t < CHUNK; ++t) {
        const f32x4* hv = reinterpret_cast<const f32x4*>(hb[cur]);
        f32x4 s0{}, s1{}, s2{}, s3{};
        #pragma unroll
        for (int k = 0; k < 32; k += 4) {
            s0 += ar[k]     * hv[k];
            s1 += ar[k + 1] * hv[k + 1];
            s2 += ar[k + 2] * hv[k + 2];
            s3 += ar[k + 3] * hv[k + 3];
        }
        f32x4 ss = (s0 + s1) + (s2 + s3);
        float val = ss[0] + ss[1] + ss[2] + ss[3] + __bfloat162float(uL[t * 128 + tid]);
        hs[(tok0 + t) * 128 + tid] = __float2bfloat16(val);
        hb[cur ^ 1][tid] = val;
        __syncthreads();
        cur ^= 1;
    }
}

// ---------------- host ----------------
extern "C" void kernel_launch(void* const* d_in, const int* in_sizes, int n_in,
                              void* d_out, int out_size, void* d_ws, size_t ws_size,
                              hipStream_t stream) {
    const float* x    = (const float*)d_in[0];
    const float* A    = (const float*)d_in[1];
    const float* B_w  = (const float*)d_in[2];
    const float* B_b  = (const float*)d_in[3];
    const float* C_w  = (const float*)d_in[4];
    const float* C_b  = (const float*)d_in[5];
    const float* D_w  = (const float*)d_in[6];
    const float* D_b  = (const float*)d_in[7];
    const float* s_w1 = (const float*)d_in[8];
    const float* s_b1 = (const float*)d_in[9];
    const float* s_w2 = (const float*)d_in[10];
    const float* s_b2 = (const float*)d_in[11];
    const float* g_w  = (const float*)d_in[12];
    const float* g_b  = (const float*)d_in[13];
    float* out = (float*)d_out;

    char* p = (char*)d_ws;
    auto alloc = [&](size_t n) { char* r = p; p += (n + 255) & ~(size_t)255; return r; };
    __hip_bfloat16* xb    = (__hip_bfloat16*)alloc((size_t)M_TOK * 1024 * 2);
    __hip_bfloat16* w1b   = (__hip_bfloat16*)alloc(512 * 1024 * 2);
    __hip_bfloat16* w2b   = (__hip_bfloat16*)alloc(128 * 512 * 2);
    __hip_bfloat16* Bwb   = (__hip_bfloat16*)alloc(128 * 1024 * 2);
    __hip_bfloat16* Cwb   = (__hip_bfloat16*)alloc(1024 * 128 * 2);
    __hip_bfloat16* Dwb   = (__hip_bfloat16*)alloc(1024 * 1024 * 2);
    __hip_bfloat16* gwb   = (__hip_bfloat16*)alloc(1024 * 1024 * 2);
    __hip_bfloat16* z1b   = (__hip_bfloat16*)alloc((size_t)M_TOK * 512 * 2);
    __hip_bfloat16* ub    = (__hip_bfloat16*)alloc((size_t)M_TOK * 128 * 2);
    __hip_bfloat16* hsb   = (__hip_bfloat16*)alloc((size_t)M_TOK * 128 * 2);
    float* pb       = (float*)alloc(128 * 128 * 4);
    float* Ebuf     = (float*)alloc(512 * 128 * 4);
    float* startbuf = (float*)alloc(512 * 128 * 4);

    // fused: A^32 (blocks 0..127) + all converts (blocks 128..9759)
    conv_pow<<<dim3(9760), dim3(256), 0, stream>>>(
        A, pb,
        x, s_w1, s_w2, B_w, C_w, D_w, g_w,
        xb, w1b, w2b, Bwb, Cwb, Dwb, gwb);

    // z1 = silu(x @ s_w1^T + s_b1)   — 512 blocks
    gemm128<0><<<dim3(512), dim3(256), 0, stream>>>(
        xb, w1b, nullptr, nullptr, nullptr, s_b1, nullptr, nullptr, nullptr, z1b);
    // u GEMM + fused scan phase-1 — 512 blocks
    gemm_u<<<dim3(512), dim3(256), 0, stream>>>(z1b, w2b, s_b2, xb, Bwb, B_b, A, ub, Ebuf);

    // scan phase 2 + 3
    ssm_phase2<<<8, 128, 0, stream>>>(pb, Ebuf, startbuf);
    ssm_phase3<<<512, 128, 0, stream>>>(A, ub, startbuf, hsb);

    // out = (x@D^T + Db + hs@C^T + Cb) * sigmoid(x@g^T + gb) — 1024 blocks
    gemm128<1><<<dim3(1024), dim3(256), 0, stream>>>(
        xb, Dwb, gwb, hsb, Cwb, D_b, C_b, g_b, out, nullptr);
}

// Round 19
// 200.768 us; speedup vs baseline: 1.0294x; 1.0294x over previous
//
#include <hip/hip_runtime.h>
#include <hip/hip_bf16.h>

typedef __bf16 bf16x8 __attribute__((ext_vector_type(8)));
typedef float f32x4 __attribute__((ext_vector_type(4)));

#define M_TOK 16384   // 8 * 2048 tokens
#define CHUNK 32
#define NCHUNK 64     // 2048 / 32

__device__ __forceinline__ void gload16(const void* g, void* l) {
    __builtin_amdgcn_global_load_lds(
        (const __attribute__((address_space(1))) void*)g,
        (__attribute__((address_space(3))) void*)l, 16, 0, 0);
}

__device__ __forceinline__ float sigmoidf_(float v) { return 1.f / (1.f + __expf(-v)); }

// ======== fused: matpow32 (blocks 0..127, dispatched FIRST) + all converts (128..9759) ========
__global__ __launch_bounds__(256)
void conv_pow(const float* __restrict__ A, float* __restrict__ A32,
              const float* s0, const float* s1, const float* s2, const float* s3,
              const float* s4, const float* s5, const float* s6,
              __hip_bfloat16* d0, __hip_bfloat16* d1, __hip_bfloat16* d2,
              __hip_bfloat16* d3, __hip_bfloat16* d4, __hip_bfloat16* d5,
              __hip_bfloat16* d6) {
    __shared__ __align__(16) float v[2][128];
    const int tid = threadIdx.x;
    if (blockIdx.x < 128) {
        const int col = blockIdx.x;
        f32x4 pr[32];
        if (tid < 128) {
            #pragma unroll
            for (int k = 0; k < 32; ++k)
                pr[k] = *reinterpret_cast<const f32x4*>(&A[tid * 128 + k * 4]);
            v[0][tid] = A[tid * 128 + col];
        }
        __syncthreads();
        int cur = 0;
        for (int it = 0; it < 31; ++it) {
            if (tid < 128) {
                const f32x4* hv = reinterpret_cast<const f32x4*>(v[cur]);
                f32x4 s0_{}, s1_{}, s2_{}, s3_{};
                #pragma unroll
                for (int k = 0; k < 32; k += 4) {
                    s0_ += pr[k]     * hv[k];
                    s1_ += pr[k + 1] * hv[k + 1];
                    s2_ += pr[k + 2] * hv[k + 2];
                    s3_ += pr[k + 3] * hv[k + 3];
                }
                f32x4 ss = (s0_ + s1_) + (s2_ + s3_);
                v[cur ^ 1][tid] = ss[0] + ss[1] + ss[2] + ss[3];
            }
            __syncthreads();
            cur ^= 1;
        }
        if (tid < 128) A32[tid * 128 + col] = v[cur][tid];
        return;
    }
    const int bid = blockIdx.x - 128;
    const float* s; __hip_bfloat16* d; int base;
    if      (bid < 8192) { s = s0; d = d0; base = 0;    }
    else if (bid < 8448) { s = s1; d = d1; base = 8192; }
    else if (bid < 8480) { s = s2; d = d2; base = 8448; }
    else if (bid < 8544) { s = s3; d = d3; base = 8480; }
    else if (bid < 8608) { s = s4; d = d4; base = 8544; }
    else if (bid < 9120) { s = s5; d = d5; base = 8608; }
    else                 { s = s6; d = d6; base = 9120; }
    size_t i = (size_t)(bid - base) * 256 + tid;
    const f32x4* p4 = reinterpret_cast<const f32x4*>(s) + i * 2;
    f32x4 a = p4[0], b = p4[1];
    union { __hip_bfloat16 h[8]; uint4 u; } o;
    o.h[0] = __float2bfloat16(a[0]); o.h[1] = __float2bfloat16(a[1]);
    o.h[2] = __float2bfloat16(a[2]); o.h[3] = __float2bfloat16(a[3]);
    o.h[4] = __float2bfloat16(b[0]); o.h[5] = __float2bfloat16(b[1]);
    o.h[6] = __float2bfloat16(b[2]); o.h[7] = __float2bfloat16(b[3]);
    *reinterpret_cast<uint4*>(d + i * 8) = o.u;
}

// ================= 128x128 m97-style GEMM (single-buffer, multi-block overlap) =========
// MODE 0: z1 = silu(X@W^T + b)        -> bf16 (N=512, K=1024)
// MODE 1: out = (X@Dw^T + Db + HS@Cw^T + Cb) * sigmoid(X@Gw^T + Gb) -> f32 (N=1024)
// 930 TF (R7). launch_bounds STAYS (256,2): R16 proved (256,3/4) caps VGPR at 84 -> spills.
template<int MODE>
__global__ __launch_bounds__(256, 2)
void gemm128(const __hip_bfloat16* __restrict__ X, const __hip_bfloat16* __restrict__ W,
             const __hip_bfloat16* __restrict__ Gw, const __hip_bfloat16* __restrict__ HS,
             const __hip_bfloat16* __restrict__ CW,
             const float* __restrict__ bias, const float* __restrict__ bias2,
             const float* __restrict__ biasG,
             float* __restrict__ outF, __hip_bfloat16* __restrict__ outB) {
    constexpr int N = (MODE == 0) ? 512 : 1024;
    constexpr int nN = N / 128;
    __shared__ __align__(16) char Xs[16384];
    __shared__ __align__(16) char Ws[16384];
    __shared__ __align__(16) char Gs[(MODE == 1) ? 16384 : 16];

    const int nwg  = gridDim.x;
    const int orig = blockIdx.x;
    const int v    = (orig & 7) * (nwg >> 3) + (orig >> 3);   // XCD-bijective (nwg%8==0)
    const size_t m0 = (size_t)(v / nN) * 128;
    const int    n0 = (v % nN) * 128;
    const int tid = threadIdx.x, lane = tid & 63, wid = tid >> 6;
    const int wm = wid >> 1, wn = wid & 1;
    const int lr = lane & 15, lg = lane >> 4;

    auto frag = [&](const char* base, int R, int kk) -> bf16x8 {
        int cb = (kk * 64 + lg * 16) ^ ((R & 7) << 4);
        return *reinterpret_cast<const bf16x8*>(base + R * 128 + cb);
    };

    const char* gx[4]; const char* gw[4]; const char* gg[4];
    char* lx[4]; char* lw[4]; char* lg_[4];
    int rowq[4], cbq[4];
    #pragma unroll
    for (int j = 0; j < 4; ++j) {
        int q = tid + 256 * j;
        rowq[j] = q >> 3;
        cbq[j] = ((q & 7) * 16) ^ ((rowq[j] & 7) << 4);
        gx[j] = (const char*)(X + (m0 + rowq[j]) * (size_t)1024) + cbq[j];
        gw[j] = (const char*)(W + ((size_t)(n0 + rowq[j])) * 1024) + cbq[j];
        if constexpr (MODE == 1)
            gg[j] = (const char*)(Gw + ((size_t)(n0 + rowq[j])) * 1024) + cbq[j];
        lx[j] = Xs + q * 16; lw[j] = Ws + q * 16; lg_[j] = Gs + q * 16;
    }

    f32x4 accY[4][4] = {};
    f32x4 accG[(MODE == 1) ? 4 : 1][4] = {};

    for (int k0 = 0; k0 < 1024; k0 += 64) {
        __syncthreads();
        #pragma unroll
        for (int j = 0; j < 4; ++j) { gload16(gx[j], lx[j]); gx[j] += 128; }
        #pragma unroll
        for (int j = 0; j < 4; ++j) { gload16(gw[j], lw[j]); gw[j] += 128; }
        if constexpr (MODE == 1) {
            #pragma unroll
            for (int j = 0; j < 4; ++j) { gload16(gg[j], lg_[j]); gg[j] += 128; }
        }
        __syncthreads();
        #pragma unroll
        for (int kk = 0; kk < 2; ++kk) {
            bf16x8 af[4];
            #pragma unroll
            for (int m = 0; m < 4; ++m) af[m] = frag(Xs, wm*64 + m*16 + lr, kk);
            #pragma unroll
            for (int n = 0; n < 4; ++n) {
                bf16x8 bw = frag(Ws, wn*64 + n*16 + lr, kk);
                #pragma unroll
                for (int m = 0; m < 4; ++m)
                    accY[m][n] = __builtin_amdgcn_mfma_f32_16x16x32_bf16(af[m], bw, accY[m][n], 0, 0, 0);
                if constexpr (MODE == 1) {
                    bf16x8 bg = frag(Gs, wn*64 + n*16 + lr, kk);
                    #pragma unroll
                    for (int m = 0; m < 4; ++m)
                        accG[m][n] = __builtin_amdgcn_mfma_f32_16x16x32_bf16(af[m], bg, accG[m][n], 0, 0, 0);
                }
            }
        }
    }
    if constexpr (MODE == 1) {
        #pragma unroll
        for (int j = 0; j < 4; ++j) {
            gx[j] = (const char*)(HS + (m0 + rowq[j]) * (size_t)128) + cbq[j];
            gw[j] = (const char*)(CW + ((size_t)(n0 + rowq[j])) * 128) + cbq[j];
        }
        for (int k0 = 0; k0 < 128; k0 += 64) {
            __syncthreads();
            #pragma unroll
            for (int j = 0; j < 4; ++j) { gload16(gx[j], lx[j]); gx[j] += 128; }
            #pragma unroll
            for (int j = 0; j < 4; ++j) { gload16(gw[j], lw[j]); gw[j] += 128; }
            __syncthreads();
            #pragma unroll
            for (int kk = 0; kk < 2; ++kk) {
                bf16x8 af[4];
                #pragma unroll
                for (int m = 0; m < 4; ++m) af[m] = frag(Xs, wm*64 + m*16 + lr, kk);
                #pragma unroll
                for (int n = 0; n < 4; ++n) {
                    bf16x8 bw = frag(Ws, wn*64 + n*16 + lr, kk);
                    #pragma unroll
                    for (int m = 0; m < 4; ++m)
                        accY[m][n] = __builtin_amdgcn_mfma_f32_16x16x32_bf16(af[m], bw, accY[m][n], 0, 0, 0);
                }
            }
        }
    }

    #pragma unroll
    for (int m = 0; m < 4; ++m)
        #pragma unroll
        for (int n = 0; n < 4; ++n)
            #pragma unroll
            for (int rr = 0; rr < 4; ++rr) {
                size_t row = m0 + wm*64 + m*16 + lg*4 + rr;
                int col = n0 + wn*64 + n*16 + lr;
                if constexpr (MODE == 0) {
                    float vv = accY[m][n][rr] + bias[col];
                    outB[row * N + col] = __float2bfloat16(vv * sigmoidf_(vv));
                } else {
                    float y = accY[m][n][rr] + bias[col] + bias2[col];
                    float g = accG[m][n][rr] + biasG[col];
                    outF[row * 1024 + col] = y * sigmoidf_(g);
                }
            }
}

// ----- u = (x@B_w^T + B_b) * sigmoid(z1@s_w2^T + s_b2)   [16384,128], 32-row tiles -----
// 512 blocks, 2 blocks/CU (R15-proven). R18 lesson: do NOT fuse the scan tail in — with
// all blocks co-resident a serial tail is additive either way; fusion only saved a gap
// while adding VGPR pressure (200.9 -> 206.7).
__global__ __launch_bounds__(256, 2)
void gemm_u(const __hip_bfloat16* __restrict__ Z1, const __hip_bfloat16* __restrict__ W2,
            const float* __restrict__ b2,
            const __hip_bfloat16* __restrict__ X, const __hip_bfloat16* __restrict__ Bw,
            const float* __restrict__ Bb, __hip_bfloat16* __restrict__ U) {
    __shared__ __align__(16) char As[32 * 128];    // 4 KB
    __shared__ __align__(16) char Bs[128 * 128];   // 16 KB
    const int orig = blockIdx.x;                 // nwg = 512
    const int v = (orig & 7) * 64 + (orig >> 3);
    const int m0 = v * 32;
    const int tid = threadIdx.x;
    const int wid = tid >> 6, lane = tid & 63;
    const int wm = wid >> 1, wn = wid & 1;
    const int lr = lane & 15, lg = lane >> 4;

    auto fragA = [&](int R, int kk) -> bf16x8 {
        int cb = (kk * 64 + lg * 16) ^ ((R & 7) << 4);
        return *reinterpret_cast<const bf16x8*>(As + R * 128 + cb);
    };
    auto fragB = [&](int R, int kk) -> bf16x8 {
        int cb = (kk * 64 + lg * 16) ^ ((R & 7) << 4);
        return *reinterpret_cast<const bf16x8*>(Bs + R * 128 + cb);
    };

    const int rowA = tid >> 3, cbA = ((tid & 7) * 16) ^ ((rowA & 7) << 4);
    char* lA = As + tid * 16;
    int rowB[4], cbB[4]; char* lB[4];
    #pragma unroll
    for (int j = 0; j < 4; ++j) {
        int q = tid + 256 * j;
        rowB[j] = q >> 3; cbB[j] = ((q & 7) * 16) ^ ((rowB[j] & 7) << 4);
        lB[j] = Bs + q * 16;
    }

    const char* ga; const char* gb[4];
    ga = (const char*)(Z1 + (size_t)(m0 + rowA) * 512) + cbA;
    #pragma unroll
    for (int j = 0; j < 4; ++j) gb[j] = (const char*)(W2 + (size_t)rowB[j] * 512) + cbB[j];

    f32x4 accS[4] = {};
    for (int k0 = 0; k0 < 512; k0 += 64) {
        __syncthreads();
        gload16(ga, lA); ga += 128;
        #pragma unroll
        for (int j = 0; j < 4; ++j) { gload16(gb[j], lB[j]); gb[j] += 128; }
        __syncthreads();
        #pragma unroll
        for (int kk = 0; kk < 2; ++kk) {
            bf16x8 af = fragA(wm*16 + lr, kk);
            #pragma unroll
            for (int n = 0; n < 4; ++n) {
                bf16x8 bf_ = fragB(wn*64 + n*16 + lr, kk);
                accS[n] = __builtin_amdgcn_mfma_f32_16x16x32_bf16(af, bf_, accS[n], 0, 0, 0);
            }
        }
    }
    #pragma unroll
    for (int n = 0; n < 4; ++n)
        #pragma unroll
        for (int r = 0; r < 4; ++r) {
            int col = wn*64 + n*16 + lr;
            accS[n][r] = sigmoidf_(accS[n][r] + b2[col]);
        }
    ga = (const char*)(X + (size_t)(m0 + rowA) * 1024) + cbA;
    #pragma unroll
    for (int j = 0; j < 4; ++j) gb[j] = (const char*)(Bw + (size_t)rowB[j] * 1024) + cbB[j];
    f32x4 accU[4] = {};
    for (int k0 = 0; k0 < 1024; k0 += 64) {
        __syncthreads();
        gload16(ga, lA); ga += 128;
        #pragma unroll
        for (int j = 0; j < 4; ++j) { gload16(gb[j], lB[j]); gb[j] += 128; }
        __syncthreads();
        #pragma unroll
        for (int kk = 0; kk < 2; ++kk) {
            bf16x8 af = fragA(wm*16 + lr, kk);
            #pragma unroll
            for (int n = 0; n < 4; ++n) {
                bf16x8 bf_ = fragB(wn*64 + n*16 + lr, kk);
                accU[n] = __builtin_amdgcn_mfma_f32_16x16x32_bf16(af, bf_, accU[n], 0, 0, 0);
            }
        }
    }
    #pragma unroll
    for (int n = 0; n < 4; ++n)
        #pragma unroll
        for (int r = 0; r < 4; ++r) {
            int row = m0 + wm*16 + lg*4 + r;
            int col = wn*64 + n*16 + lr;
            float uval = (accU[n][r] + Bb[col]) * accS[n][r];
            U[(size_t)row * 128 + col] = __float2bfloat16(uval);
        }
}

// ---------------- scan phase 1: CHUNK=32, 512 blocks; A-row in REGISTERS ----------------
__global__ __launch_bounds__(128, 1) void ssm_phase1(const float* __restrict__ A,
                                                     const __hip_bfloat16* __restrict__ u,
                                                     float* __restrict__ E) {
    __shared__ __align__(16) float hb[2][128];
    __shared__ __align__(16) __hip_bfloat16 uL[CHUNK * 128];   // 8 KB
    const int tid = threadIdx.x;
    f32x4 ar[32];
    #pragma unroll
    for (int k = 0; k < 32; ++k) ar[k] = *reinterpret_cast<const f32x4*>(&A[tid * 128 + k * 4]);
    const int b = blockIdx.x >> 6, c = blockIdx.x & 63;
    const __hip_bfloat16* up = u + ((size_t)b * 2048 + c * CHUNK) * 128;
    #pragma unroll
    for (int q = 0; q < 4; ++q)
        gload16(up + ((size_t)(q * 128 + tid)) * 8, &uL[(q * 128 + tid) * 8]);
    hb[0][tid] = 0.f;
    __syncthreads();
    int cur = 0;
    for (int t = 0; t < CHUNK; ++t) {
        const f32x4* hv = reinterpret_cast<const f32x4*>(hb[cur]);
        f32x4 s0{}, s1{}, s2{}, s3{};
        #pragma unroll
        for (int k = 0; k < 32; k += 4) {
            s0 += ar[k]     * hv[k];
            s1 += ar[k + 1] * hv[k + 1];
            s2 += ar[k + 2] * hv[k + 2];
            s3 += ar[k + 3] * hv[k + 3];
        }
        f32x4 ss = (s0 + s1) + (s2 + s3);
        float val = ss[0] + ss[1] + ss[2] + ss[3] + __bfloat162float(uL[t * 128 + tid]);
        hb[cur ^ 1][tid] = val;
        __syncthreads();
        cur ^= 1;
    }
    E[(size_t)blockIdx.x * 128 + tid] = hb[cur][tid];
}

// ---------------- phase 2: per-batch combine over 64 chunks with A^32 ----------------
__global__ __launch_bounds__(128, 1) void ssm_phase2(const float* __restrict__ A32,
                                                     const float* __restrict__ E,
                                                     float* __restrict__ starts) {
    __shared__ __align__(16) float st[2][128];
    __shared__ __align__(16) float El[NCHUNK * 128];   // 32 KB
    const int tid = threadIdx.x, b = blockIdx.x;       // 8 blocks
    f32x4 ar[32];
    #pragma unroll
    for (int k = 0; k < 32; ++k) ar[k] = *reinterpret_cast<const f32x4*>(&A32[tid * 128 + k * 4]);
    const f32x4* Eg = reinterpret_cast<const f32x4*>(E + (size_t)b * NCHUNK * 128);
    #pragma unroll
    for (int q = 0; q < 16; ++q)
        reinterpret_cast<f32x4*>(El)[q * 128 + tid] = Eg[q * 128 + tid];
    st[0][tid] = 0.f;
    __syncthreads();
    int cur = 0;
    for (int c = 0; c < NCHUNK; ++c) {
        starts[((size_t)b * NCHUNK + c) * 128 + tid] = st[cur][tid];
        const f32x4* hv = reinterpret_cast<const f32x4*>(st[cur]);
        f32x4 s0{}, s1{}, s2{}, s3{};
        #pragma unroll
        for (int k = 0; k < 32; k += 4) {
            s0 += ar[k]     * hv[k];
            s1 += ar[k + 1] * hv[k + 1];
            s2 += ar[k + 2] * hv[k + 2];
            s3 += ar[k + 3] * hv[k + 3];
        }
        f32x4 ss = (s0 + s1) + (s2 + s3);
        float val = ss[0] + ss[1] + ss[2] + ss[3] + El[c * 128 + tid];
        st[cur ^ 1][tid] = val;
        __syncthreads();
        cur ^= 1;
    }
}

// ---------------- phase 3: re-run from starts, emit hs; CHUNK=32, 512 blocks ----------------
__global__ __launch_bounds__(128, 1) void ssm_phase3(const float* __restrict__ A,
                                                     const __hip_bfloat16* __restrict__ u,
                                                     const float* __restrict__ starts,
                                                     __hip_bfloat16* __restrict__ hs) {
    __shared__ __align__(16) float hb[2][128];
    __shared__ __align__(16) __hip_bfloat16 uL[CHUNK * 128];   // 8 KB
    const int tid = threadIdx.x;
    f32x4 ar[32];
    #pragma unroll
    for (int k = 0; k < 32; ++k) ar[k] = *reinterpret_cast<const f32x4*>(&A[tid * 128 + k * 4]);
    const int b = blockIdx.x >> 6, c = blockIdx.x & 63;
    const size_t tok0 = (size_t)b * 2048 + c * CHUNK;
    const __hip_bfloat16* up = u + tok0 * 128;
    #pragma unroll
    for (int q = 0; q < 4; ++q)
        gload16(up + ((size_t)(q * 128 + tid)) * 8, &uL[(q * 128 + tid) * 8]);
    hb[0][tid] = starts[(size_t)blockIdx.x * 128 + tid];
    __syncthreads();
    int cur = 0;
    for (int t = 0; t < CHUNK; ++t) {
        const f32x4* hv = reinterpret_cast<const f32x4*>(hb[cur]);
        f32x4 s0{}, s1{}, s2{}, s3{};
        #pragma unroll
        for (int k = 0; k < 32; k += 4) {
            s0 += ar[k]     * hv[k];
            s1 += ar[k + 1] * hv[k + 1];
            s2 += ar[k + 2] * hv[k + 2];
            s3 += ar[k + 3] * hv[k + 3];
        }
        f32x4 ss = (s0 + s1) + (s2 + s3);
        float val = ss[0] + ss[1] + ss[2] + ss[3] + __bfloat162float(uL[t * 128 + tid]);
        hs[(tok0 + t) * 128 + tid] = __float2bfloat16(val);
        hb[cur ^ 1][tid] = val;
        __syncthreads();
        cur ^= 1;
    }
}

// ---------------- host ----------------
extern "C" void kernel_launch(void* const* d_in, const int* in_sizes, int n_in,
                              void* d_out, int out_size, void* d_ws, size_t ws_size,
                              hipStream_t stream) {
    const float* x    = (const float*)d_in[0];
    const float* A    = (const float*)d_in[1];
    const float* B_w  = (const float*)d_in[2];
    const float* B_b  = (const float*)d_in[3];
    const float* C_w  = (const float*)d_in[4];
    const float* C_b  = (const float*)d_in[5];
    const float* D_w  = (const float*)d_in[6];
    const float* D_b  = (const float*)d_in[7];
    const float* s_w1 = (const float*)d_in[8];
    const float* s_b1 = (const float*)d_in[9];
    const float* s_w2 = (const float*)d_in[10];
    const float* s_b2 = (const float*)d_in[11];
    const float* g_w  = (const float*)d_in[12];
    const float* g_b  = (const float*)d_in[13];
    float* out = (float*)d_out;

    char* p = (char*)d_ws;
    auto alloc = [&](size_t n) { char* r = p; p += (n + 255) & ~(size_t)255; return r; };
    __hip_bfloat16* xb    = (__hip_bfloat16*)alloc((size_t)M_TOK * 1024 * 2);
    __hip_bfloat16* w1b   = (__hip_bfloat16*)alloc(512 * 1024 * 2);
    __hip_bfloat16* w2b   = (__hip_bfloat16*)alloc(128 * 512 * 2);
    __hip_bfloat16* Bwb   = (__hip_bfloat16*)alloc(128 * 1024 * 2);
    __hip_bfloat16* Cwb   = (__hip_bfloat16*)alloc(1024 * 128 * 2);
    __hip_bfloat16* Dwb   = (__hip_bfloat16*)alloc(1024 * 1024 * 2);
    __hip_bfloat16* gwb   = (__hip_bfloat16*)alloc(1024 * 1024 * 2);
    __hip_bfloat16* z1b   = (__hip_bfloat16*)alloc((size_t)M_TOK * 512 * 2);
    __hip_bfloat16* ub    = (__hip_bfloat16*)alloc((size_t)M_TOK * 128 * 2);
    __hip_bfloat16* hsb   = (__hip_bfloat16*)alloc((size_t)M_TOK * 128 * 2);
    float* pb       = (float*)alloc(128 * 128 * 4);
    float* Ebuf     = (float*)alloc(512 * 128 * 4);
    float* startbuf = (float*)alloc(512 * 128 * 4);

    // fused: A^32 (blocks 0..127) + all converts (blocks 128..9759)
    conv_pow<<<dim3(9760), dim3(256), 0, stream>>>(
        A, pb,
        x, s_w1, s_w2, B_w, C_w, D_w, g_w,
        xb, w1b, w2b, Bwb, Cwb, Dwb, gwb);

    // z1 = silu(x @ s_w1^T + s_b1)   — 512 blocks
    gemm128<0><<<dim3(512), dim3(256), 0, stream>>>(
        xb, w1b, nullptr, nullptr, nullptr, s_b1, nullptr, nullptr, nullptr, z1b);
    // u = (x @ B_w^T + B_b) * sigmoid(z1 @ s_w2^T + s_b2) — 512 blocks
    gemm_u<<<dim3(512), dim3(256), 0, stream>>>(z1b, w2b, s_b2, xb, Bwb, B_b, ub);

    // chunked scan, CHUNK=32
    ssm_phase1<<<512, 128, 0, stream>>>(A, ub, Ebuf);
    ssm_phase2<<<8, 128, 0, stream>>>(pb, Ebuf, startbuf);
    ssm_phase3<<<512, 128, 0, stream>>>(A, ub, startbuf, hsb);

    // out = (x@D^T + Db + hs@C^T + Cb) * sigmoid(x@g^T + gb) — 1024 blocks
    gemm128<1><<<dim3(1024), dim3(256), 0, stream>>>(
        xb, Dwb, gwb, hsb, Cwb, D_b, C_b, g_b, out, nullptr);
}